// Round 9
// baseline (2315.278 us; speedup 1.0000x reference)
//
#include <hip/hip_runtime.h>
#include <stdint.h>

#define NB 16
#define HH 128
#define WW 128
#define L (HH*WW)        // 16384
#define CIN 3
#define HID 256
#define NC 21
#define CHUNK 256
#define NCHUNKS (L/CHUNK)   // 64
#define T_PER 32            // t's per wave in k_bp
#define NPACK (L/4)         // 4096 packs of 4 timesteps

// ---------------- K1: conv -> fp32 emissions, TRANSPOSED em_T[b][c][t], LDS input tile ----------------
__global__ __launch_bounds__(256) void k_conv(
    const float* __restrict__ x, const float* __restrict__ w1,
    const float* __restrict__ b1, const float* __restrict__ w2,
    const float* __restrict__ b2, float* __restrict__ emT)
{
    __shared__ float xs[CIN*4*WW];        // 3 ic x 4 rows x 128 cols = 6144 B
    int tid = threadIdx.x;
    int g  = blockIdx.x * 256 + tid;      // 0..B*L-1
    int b  = g >> 14;
    int t0 = (blockIdx.x * 256) & (L-1);  // first t of block (multiple of 256)
    int y0 = t0 >> 7;                     // first of the block's 2 rows
    int dy = tid >> 7;                    // 0 or 1
    int xx = tid & (WW-1);
    int t  = t0 + tid;

    const float* xb = x + (size_t)b * CIN * L;
    for (int i = tid; i < CIN*4*WW; i += 256) {
        int ic  = i >> 9;                 // /512
        int rem = i & 511;
        int rr  = rem >> 7;               // 0..3
        int cc  = rem & 127;
        int row = y0 - 1 + rr;
        xs[i] = (row >= 0 && row < HH) ? xb[ic*L + (row<<7) + cc] : 0.f;
    }
    __syncthreads();

    double p[27];
    #pragma unroll
    for (int ic = 0; ic < CIN; ++ic) {
        #pragma unroll
        for (int ky = 0; ky < 3; ++ky) {
            #pragma unroll
            for (int kx = 0; kx < 3; ++kx) {
                int xc = xx + kx - 1;
                float v = (xc >= 0 && xc < WW) ? xs[ic*512 + (dy+ky)*128 + xc] : 0.f;
                p[ic*9 + ky*3 + kx] = (double)v;
            }
        }
    }

    double acc[NC];
    #pragma unroll
    for (int c = 0; c < NC; ++c) acc[c] = 0.0;

    #pragma unroll 2
    for (int oc = 0; oc < HID; ++oc) {
        double hv = 0.0;                              // conv1 accum
        #pragma unroll
        for (int j = 0; j < 27; ++j) hv += (double)w1[oc*27 + j] * p[j];
        float h32 = (float)hv;                        // round conv1 to fp32
        h32 = h32 + b1[oc];                           // fp32 elementwise bias
        h32 = fmaxf(h32, 0.f);                        // relu (fp32)
        double hd = (double)h32;
        #pragma unroll
        for (int c = 0; c < NC; ++c) acc[c] += (double)w2[c*HID + oc] * hd;
    }
    float* dstb = emT + (size_t)b * NC * L;
    #pragma unroll
    for (int c = 0; c < NC; ++c) {
        float e32 = (float)acc[c];                    // round conv2 to fp32
        dstb[(size_t)c * L + t] = e32 + b2[c];        // transposed store (coalesced in t)
    }
}

// ---------------- K2a: 2-half permlane recursion — plain LDS, no atomics, reg-resident sc ----------
// RESUBMIT of R8 (container failed twice = R4's infra-flake signature; R4's identical source
// passed in R5 on resubmit). Re-audit: LDS idx <= 151 < 256; write idx <= 148 / dump <= 127
// (dump region never read); window bases byte-aligned {0,48,512,560}; pads 21-23 stay -inf,
// -inf + -inf = -inf (no NaN); permlane32_swap identical to R2/R3 (both passed).
// s'[n] = fl( max_p fl(s[p]+T[p][n]) + e[n] ) — bitwise equal to ref by RNE monotonicity:
// half h covers W_h (h0: p 0-11, h1: p 12-20 +3 pads), q_h = fl(max_{W_h} fl(s+T) + e)
// = max_{W_h} fl(fl(s+T)+e); fmax(q_0,q_1) (via permlane32_swap both-results trick, R2-proven)
// = exact 21-way value, IN REGISTER in every lane.
// Ledger (cy/step): R11=314, R2=346, R1=421, R3=551, R5=237, R6=325, R7=229 (prev best).
// R7's remaining fat: 3-way same-addr ds_max RMW (32cy conflict counter) + ds_wrxchg. R8 kills
// both: DS pipe/step = 3 broadcast ds_read_b128 (12-float window, aligned) + 1 plain
// ds_write_b32 (21 distinct addrs + dumps) — no RMW, no exchange, no readback (the writer holds
// s_t[n] in register -> sc quads stored straight from regs, no lag). Est ~190-200 cy/step.
#define NEGINF (-__builtin_huge_valf())
typedef int iv2 __attribute__((ext_vector_type(2)));

__global__ __launch_bounds__(64) void k_scores(
    const float* __restrict__ emT, const float* __restrict__ start,
    const float* __restrict__ endt, const float* __restrict__ trans,
    float* __restrict__ sc, int* __restrict__ last_tag)
{
    __shared__ float smem[256];            // buf0 @ [0,128), buf1 @ [128,256); state [0,24)+[128,152)
    __shared__ float fin[NC];
    int l = threadIdx.x;
    int b = blockIdx.x;
    int u = l & 31;
    int h = l >> 5;                        // half 0: lanes 0-31, half 1: lanes 32-63
    int n = u < NC ? u : NC-1;             // lanes 21-31/53-63 shadow n=20 (consistent dups)
    int wb = 12*h;                         // window floats [12h, 12h+12)

    // write offset: half-0 state lanes own slot n; everyone else dumps into [64,128) (never read)
    int woff_dump = 64 + l;                // 64..127, distinct per lane
    bool writer = (h == 0) && (u < NC);

    const float4* er4 = (const float4*)(emT + ((size_t)b * NC + n) * L);
    float*        scp = sc + (size_t)b * NC * L;          // 84 floats per pack

    // 12 transition constants T[12h+i][n]; -inf for p>20 (h1 pads i=9,10,11)
    float tcv[12];
    #pragma unroll
    for (int i = 0; i < 12; ++i) {
        int p = wb + i;
        tcv[i] = (p < NC) ? trans[p*NC + n] : NEGINF;
    }
    #pragma unroll
    for (int i = 0; i < 12; ++i) asm volatile("" : "+v"(tcv[i]));

    // STEP(CUR,NXT): 3 window b128 reads of CUR; 12 add + max3 tree + add e -> q_h;
    // permlane32_swap + fmax -> s_t[n] (all lanes); plain write into NXT (writers only).
    #define STEP(CUR, NXT, EV, OUT) { \
        float4 ra  = *(const float4*)&smem[(CUR)*128 + wb]; \
        float4 rb4 = *(const float4*)&smem[(CUR)*128 + wb + 4]; \
        float4 rc4 = *(const float4*)&smem[(CUR)*128 + wb + 8]; \
        float w0 = ra.x  + tcv[0], w1 = ra.y  + tcv[1], w2  = ra.z  + tcv[2],  w3  = ra.w  + tcv[3]; \
        float w4 = rb4.x + tcv[4], w5 = rb4.y + tcv[5], w6  = rb4.z + tcv[6],  w7  = rb4.w + tcv[7]; \
        float w8 = rc4.x + tcv[8], w9 = rc4.y + tcv[9], w10 = rc4.z + tcv[10], w11 = rc4.w + tcv[11]; \
        float m0 = fmaxf(fmaxf(w0, w1), w2); \
        float m1 = fmaxf(fmaxf(w3, w4), w5); \
        float m2 = fmaxf(fmaxf(w6, w7), w8); \
        float m3 = fmaxf(fmaxf(w9, w10), w11); \
        float qh = fmaxf(fmaxf(m0, m1), fmaxf(m2, m3)) + (EV);   /* q_h = fl(pr_h + e[n]) */ \
        iv2 rr = __builtin_amdgcn_permlane32_swap(__float_as_int(qh), __float_as_int(qh), false, false); \
        float sn = fmaxf(__int_as_float(rr[0]), __int_as_float(rr[1]));  /* exact 21-way, all lanes */ \
        smem[writer ? ((NXT)*128 + u) : woff_dump] = sn; \
        OUT = sn; }

    float4 ebuf0 = er4[0];
    float4 ebuf1 = er4[1];

    // ---- t=0 init + pack 0 (t=1..3) ----
    float v0 = ebuf0.x + start[n];         // s0 = fl(em[0]+start), ref order
    smem[l]       = (l < NC) ? v0 : NEGINF;   // buf0: state + -inf pads (dump region too, harmless)
    smem[128 + l] = NEGINF;                   // buf1: all -inf (pads stay forever)
    float q0 = v0, q1, q2, q3;
    {
        float4 ev = ebuf0;
        ebuf0 = er4[2];
        STEP(0, 1, ev.y, q1)               // t=1
        STEP(1, 0, ev.z, q2)               // t=2
        STEP(0, 1, ev.w, q3)               // t=3
        if (l < NC) *(float4*)(scp + n*4) = make_float4(q0, q1, q2, q3);
    }

    // ---- packs 1..4095: 4 steps then store quad straight from registers ----
    for (int k = 1; k < NPACK; ++k) {
        float4 ev = (k & 1) ? ebuf1 : ebuf0;
        int kp = k + 2; if (kp > NPACK-1) kp = NPACK-1;
        if (k & 1) ebuf1 = er4[kp]; else ebuf0 = er4[kp];

        STEP(1, 0, ev.x, q0)               // t=4k
        STEP(0, 1, ev.y, q1)               // t=4k+1
        STEP(1, 0, ev.z, q2)               // t=4k+2
        STEP(0, 1, ev.w, q3)               // t=4k+3
        if (l < NC) *(float4*)(scp + k*84 + n*4) = make_float4(q0, q1, q2, q3);
    }
    #undef STEP

    if (l < NC) fin[n] = q3;               // s_{L-1}[n] straight from register
    __syncthreads();
    if (l == 0) {
        float bv = fin[0] + endt[0]; int bt = 0;
        #pragma unroll
        for (int j = 1; j < NC; ++j) {
            float v = fin[j] + endt[j];
            if (v > bv) { bv = v; bt = j; }
        }
        last_tag[b] = bt;
    }
}

// ---------------- K2b: parallel backpointer recovery ----------------
// bp[t][n] = first p with fl(fl(s_{t-1}[p]+T[p][n])+e[t][n]) == s_t[n]
__global__ __launch_bounds__(256) void k_bp(
    const float* __restrict__ emT, const float* __restrict__ sc,
    const float* __restrict__ trans, uint8_t* __restrict__ bp)
{
    int wave = threadIdx.x >> 6;
    int lane = threadIdx.x & 63;
    int ne   = lane < NC ? lane : NC-1;

    int bidx  = blockIdx.x;
    int b     = bidx >> 7;                              // 128 blocks per batch
    int tbase = (bidx & 127) * (4*T_PER) + wave*T_PER;

    const float* emb = emT + (size_t)b * NC * L;
    const float* scp = sc  + (size_t)b * NC * L;
    uint8_t*     bpb = bp  + (size_t)b * L * NC;

    float tc[NC];
    #pragma unroll
    for (int pp = 0; pp < NC; ++pp) tc[pp] = trans[pp*NC + ne];

    for (int t = tbase; t < tbase + T_PER; ++t) {
        if (t == 0) continue;
        float target = scp[(t>>2)*84 + ne*4 + (t&3)];
        float e      = emb[(size_t)ne * L + t];
        const float* sp = scp + ((t-1)>>2)*84 + ((t-1)&3);
        int fi = 0;
        #pragma unroll
        for (int pp = NC-1; pp >= 0; --pp) {
            float cand = (sp[pp*4] + tc[pp]) + e;
            if (cand == target) fi = pp;
        }
        if (lane < NC) bpb[(size_t)t * NC + ne] = (uint8_t)fi;
    }
}

// ---------------- K3a: per-chunk jump tables, SEGMENTED chase (exact) ----------------
__global__ __launch_bounds__(64) void k_jump(
    const uint8_t* __restrict__ bp, uint8_t* __restrict__ J)
{
    __shared__ uint32_t lds4[CHUNK*NC/4];    // 5376 B of bp rows [cs..ce)
    __shared__ uint8_t  segJ[8*NC];          // 168 B
    int l   = threadIdx.x;
    int bid = blockIdx.x;
    int b   = bid / (NCHUNKS-1);
    int k   = bid % (NCHUNKS-1) + 1;         // chunks 1..63
    int cs  = k * CHUNK;

    const uint32_t* src = (const uint32_t*)(bp + (size_t)b * L * NC + (size_t)cs * NC);
    for (int i = l; i < CHUNK*NC/4; i += 64) lds4[i] = src[i];
    __syncthreads();
    const uint8_t* lb = (const uint8_t*)lds4;

    // 168 = 8 segs x 21 hyps; chase c -> (s=c/21, h=c%21), rows s*32+31 .. s*32
    int c0 = l, c1 = l + 63, c2 = l + 126;
    bool v2 = (c2 < 8*NC);
    int t0 = c0 % NC, t1 = c1 % NC, t2 = v2 ? (c2 % NC) : 0;
    int r0 = (c0 / NC) * 32, r1 = (c1 / NC) * 32, r2 = v2 ? (c2 / NC) * 32 : 0;
    for (int i = 31; i >= 0; --i) {          // 3 independent chains -> pipelined
        t0 = lb[(r0+i)*NC + t0];
        t1 = lb[(r1+i)*NC + t1];
        if (v2) t2 = lb[(r2+i)*NC + t2];
    }
    segJ[c0] = (uint8_t)t0;
    segJ[c1] = (uint8_t)t1;
    if (v2) segJ[c2] = (uint8_t)t2;
    __syncthreads();

    if (l < NC) {
        int tag = l;
        #pragma unroll
        for (int s = 7; s >= 0; --s) tag = segJ[s*NC + tag];
        J[((size_t)b * NCHUNKS + k) * NC + l] = (uint8_t)tag;
    }
}

// ---------------- K3b: thread chunk entries through jump tables (LDS-staged J) ----------------
__global__ __launch_bounds__(64) void k_seq(
    const uint8_t* __restrict__ J, const int* __restrict__ last_tag,
    uint8_t* __restrict__ ent)
{
    __shared__ uint32_t ldsJ4[NB*NCHUNKS*NC/4];   // 21504 B
    int l = threadIdx.x;
    const uint32_t* src = (const uint32_t*)J;
    for (int i = l; i < NB*NCHUNKS*NC/4; i += 64) ldsJ4[i] = src[i];
    __syncthreads();
    const uint8_t* lj = (const uint8_t*)ldsJ4;

    if (l < NB) {
        int b = l;
        int tag = last_tag[b];                       // tag at t = L-1
        ent[b * NCHUNKS + 63] = (uint8_t)tag;
        for (int k = NCHUNKS-1; k >= 1; --k) {
            tag = lj[((size_t)b * NCHUNKS + k) * NC + tag];
            ent[b * NCHUNKS + (k-1)] = (uint8_t)tag;
        }
    }
}

// ---------------- K3c: per-chunk output, SEGMENTED re-walk from exact seed ----------------
__global__ __launch_bounds__(64) void k_out(
    const uint8_t* __restrict__ bp, const uint8_t* __restrict__ ent,
    int* __restrict__ out)
{
    __shared__ uint32_t lds4[CHUNK*NC/4];
    __shared__ uint8_t  segJ[8*NC];
    __shared__ uint8_t  E[8];
    __shared__ int      tags[CHUNK];
    int l   = threadIdx.x;
    int bid = blockIdx.x;
    int b   = bid >> 6;
    int k   = bid & (NCHUNKS-1);
    int cs  = k * CHUNK;

    const uint32_t* src = (const uint32_t*)(bp + (size_t)b * L * NC + (size_t)cs * NC);
    for (int i = l; i < CHUNK*NC/4; i += 64) lds4[i] = src[i];
    __syncthreads();
    const uint8_t* lb = (const uint8_t*)lds4;

    // phase 2: segment tables (chunk 0 seg 0 crosses t=0: its result is never used)
    int c0 = l, c1 = l + 63, c2 = l + 126;
    bool v2 = (c2 < 8*NC);
    int t0 = c0 % NC, t1 = c1 % NC, t2 = v2 ? (c2 % NC) : 0;
    int r0 = (c0 / NC) * 32, r1 = (c1 / NC) * 32, r2 = v2 ? (c2 / NC) * 32 : 0;
    for (int i = 31; i >= 0; --i) {
        t0 = lb[(r0+i)*NC + t0];
        t1 = lb[(r1+i)*NC + t1];
        if (v2) t2 = lb[(r2+i)*NC + t2];
    }
    segJ[c0] = (uint8_t)(t0 & 31);           // mask: chunk-0/seg-0 garbage stays in-bounds
    segJ[c1] = (uint8_t)(t1 & 31);
    if (v2) segJ[c2] = (uint8_t)(t2 & 31);
    __syncthreads();

    // phase 3: compose segment entry tags E[s] = tag at position cs + 32s + 31
    if (l == 0) {
        int tag = ent[b * NCHUNKS + k];              // exact tag at ce-1
        E[7] = (uint8_t)tag;
        #pragma unroll
        for (int s = 7; s >= 1; --s) { tag = segJ[s*NC + tag]; E[s-1] = (uint8_t)tag; }
    }
    __syncthreads();

    // phase 4: 8 lanes re-walk their 32 rows
    if (l < 8) {
        int tag = E[l];
        int rb  = l * 32;
        for (int i = 31; i >= 0; --i) {              // t = cs+rb+i down to cs+rb
            tags[rb + i] = tag;
            tag = lb[(rb+i)*NC + tag];               // hop at t=0 (chunk 0) unused
        }
    }
    __syncthreads();

    int4* ob = (int4*)(out + (size_t)b * L + cs);
    ob[l] = ((const int4*)tags)[l];                  // 64 lanes x int4 = 256 ints
}

extern "C" void kernel_launch(void* const* d_in, const int* in_sizes, int n_in,
                              void* d_out, int out_size, void* d_ws, size_t ws_size,
                              hipStream_t stream) {
    const float* x  = (const float*)d_in[0];
    const float* w1 = (const float*)d_in[1];
    const float* b1 = (const float*)d_in[2];
    const float* w2 = (const float*)d_in[3];
    const float* b2 = (const float*)d_in[4];
    const float* st = (const float*)d_in[5];
    const float* en = (const float*)d_in[6];
    const float* tr = (const float*)d_in[7];
    int* out = (int*)d_out;

    char* ws = (char*)d_ws;
    float*   em = (float*)ws;                                    // em_T: 22,020,096 B
    float*   sc = (float*)(ws + (size_t)NB*L*NC*4);              // packed scores: 22,020,096 B
    uint8_t* bp = (uint8_t*)(ws + (size_t)NB*L*NC*8);            // 5,505,024 B
    int*     lt = (int*)(ws + (size_t)NB*L*NC*9);                // int[NB]
    // J/ent alias the em region: em is dead after k_bp completes (stream-ordered).
    uint8_t* J   = (uint8_t*)ws;                                 // NB*64*21 = 21,504 B
    uint8_t* ent = (uint8_t*)ws + 21504;                         // NB*64 = 1,024 B

    k_conv  <<<dim3(NB*L/256),       dim3(256), 0, stream>>>(x, w1, b1, w2, b2, em);
    k_scores<<<dim3(NB),             dim3(64),  0, stream>>>(em, st, en, tr, sc, lt);
    k_bp    <<<dim3(NB*128),         dim3(256), 0, stream>>>(em, sc, tr, bp);
    k_jump  <<<dim3(NB*(NCHUNKS-1)), dim3(64),  0, stream>>>(bp, J);
    k_seq   <<<dim3(1),              dim3(64),  0, stream>>>(J, lt, ent);
    k_out   <<<dim3(NB*NCHUNKS),     dim3(64),  0, stream>>>(bp, ent, out);
}

// Round 10
// 2185.491 us; speedup vs baseline: 1.0594x; 1.0594x over previous
//
#include <hip/hip_runtime.h>
#include <stdint.h>

#define NB 16
#define HH 128
#define WW 128
#define L (HH*WW)        // 16384
#define CIN 3
#define HID 256
#define NC 21
#define CHUNK 256
#define NCHUNKS (L/CHUNK)   // 64
#define T_PER 32            // t's per wave in k_bp
#define NPACK (L/4)         // 4096 packs of 4 timesteps

// ---------------- K1: conv -> fp32 emissions, TRANSPOSED em_T[b][c][t], LDS input tile ----------------
__global__ __launch_bounds__(256) void k_conv(
    const float* __restrict__ x, const float* __restrict__ w1,
    const float* __restrict__ b1, const float* __restrict__ w2,
    const float* __restrict__ b2, float* __restrict__ emT)
{
    __shared__ float xs[CIN*4*WW];        // 3 ic x 4 rows x 128 cols = 6144 B
    int tid = threadIdx.x;
    int g  = blockIdx.x * 256 + tid;      // 0..B*L-1
    int b  = g >> 14;
    int t0 = (blockIdx.x * 256) & (L-1);  // first t of block (multiple of 256)
    int y0 = t0 >> 7;                     // first of the block's 2 rows
    int dy = tid >> 7;                    // 0 or 1
    int xx = tid & (WW-1);
    int t  = t0 + tid;

    const float* xb = x + (size_t)b * CIN * L;
    for (int i = tid; i < CIN*4*WW; i += 256) {
        int ic  = i >> 9;                 // /512
        int rem = i & 511;
        int rr  = rem >> 7;               // 0..3
        int cc  = rem & 127;
        int row = y0 - 1 + rr;
        xs[i] = (row >= 0 && row < HH) ? xb[ic*L + (row<<7) + cc] : 0.f;
    }
    __syncthreads();

    double p[27];
    #pragma unroll
    for (int ic = 0; ic < CIN; ++ic) {
        #pragma unroll
        for (int ky = 0; ky < 3; ++ky) {
            #pragma unroll
            for (int kx = 0; kx < 3; ++kx) {
                int xc = xx + kx - 1;
                float v = (xc >= 0 && xc < WW) ? xs[ic*512 + (dy+ky)*128 + xc] : 0.f;
                p[ic*9 + ky*3 + kx] = (double)v;
            }
        }
    }

    double acc[NC];
    #pragma unroll
    for (int c = 0; c < NC; ++c) acc[c] = 0.0;

    #pragma unroll 2
    for (int oc = 0; oc < HID; ++oc) {
        double hv = 0.0;                              // conv1 accum
        #pragma unroll
        for (int j = 0; j < 27; ++j) hv += (double)w1[oc*27 + j] * p[j];
        float h32 = (float)hv;                        // round conv1 to fp32
        h32 = h32 + b1[oc];                           // fp32 elementwise bias
        h32 = fmaxf(h32, 0.f);                        // relu (fp32)
        double hd = (double)h32;
        #pragma unroll
        for (int c = 0; c < NC; ++c) acc[c] += (double)w2[c*HID + oc] * hd;
    }
    float* dstb = emT + (size_t)b * NC * L;
    #pragma unroll
    for (int c = 0; c < NC; ++c) {
        float e32 = (float)acc[c];                    // round conv2 to fp32
        dstb[(size_t)c * L + t] = e32 + b2[c];        // transposed store (coalesced in t)
    }
}

// ---------------- K2a: 4-buffer ring ds_max recursion (R7 chain, no wrxchg RMW) ----------------
// s'[n] = fl( max_p fl(s[p]+T[p][n]) + e[n] ) — bitwise equal to ref by RNE monotonicity:
// q_c = fl(max_{p in W_c} fl(s[p]+T) + e) = max_{W_c} fl(fl(s+T)+e); ds_max over 3 copies =
// exact 21-way value. Candidate set identical to ref -> sc bit-identical.
// Ledger (cy/step): R1=421, R2=346, R3=551, R5=237, R6=325, R7=229 (BEST), R8 permlane=283.
// Law: only the LDS ALU combines cheaply; register-side combines cost >=40cy on the chain (R8).
// R10 vs R7: the ds_wrxchg (RMW + return) is replaced by a 4-buffer ring with a PLAIN -inf
// init write one buffer ahead: step t reads B_{(t-1)%4}, maxes into B_{t%4}, inits B_{(t+1)%4}.
// sc readback comes from R6's proven 7-cndmask window select (s_{t-1}[wb..wb+8) already in regs;
// store lanes {0-7,29-36,58-62} have n in their own window — all 21 n covered exactly once).
// Ring safety: every hazard pair (init vs last read of that buffer 2 steps prior; max vs next
// read; init vs next max) is same-buffer may-alias (l / wb-range / mslot) -> compiler preserves
// order; DS pipe in-order per wave (R5/R7-proven). Pads: slots 21..63 of every buffer are -inf
// via the full-lane init writes; tc[p>20] = -inf; -inf + -inf = -inf (no NaN).
// Est ~205-220 cy/step.
#define NEGINF (-__builtin_huge_valf())

__global__ __launch_bounds__(64) void k_scores(
    const float* __restrict__ emT, const float* __restrict__ start,
    const float* __restrict__ endt, const float* __restrict__ trans,
    float* __restrict__ sc, int* __restrict__ last_tag)
{
    __shared__ float smem[256];            // 4 ring buffers of 64 floats
    __shared__ float fin[NC];
    int l = threadIdx.x;
    int b = blockIdx.x;
    int c = l / 21; if (c > 2) c = 2;      // copy 0/1/2; lanes 62,63 both map (2,20)
    int n = l - c*21; if (n > 20) n = 20;  // my state
    int wb = 8*c;                          // my p-window: floats [8c .. 8c+7]
    int mslot = (l == 63) ? 63 : n;        // lane63 maxes into dump slot 63 (3-way not 4-way)
    int ju = n - wb;                       // select index within window
    int j  = ju & 7;
    bool do_store = ((unsigned)ju < 8u) && (l != 63);   // lanes {0-7, 29-36, 58-62}

    const float4* er4 = (const float4*)(emT + ((size_t)b * NC + n) * L);
    float*        scp = sc + (size_t)b * NC * L;          // 84 floats per pack

    // 8 transition constants T[wb+i][n]; -inf for p>20 (window pad)
    float tc0, tc1, tc2, tc3, tc4, tc5, tc6, tc7;
    {
        int p0=wb, p1=wb+1, p2=wb+2, p3=wb+3, p4=wb+4, p5=wb+5, p6=wb+6, p7=wb+7;
        tc0 = trans[p0*NC + n];
        tc1 = trans[p1*NC + n];
        tc2 = trans[p2*NC + n];
        tc3 = trans[p3*NC + n];
        tc4 = trans[p4*NC + n];
        tc5 = (p5 < NC) ? trans[p5*NC + n] : NEGINF;
        tc6 = (p6 < NC) ? trans[p6*NC + n] : NEGINF;
        tc7 = (p7 < NC) ? trans[p7*NC + n] : NEGINF;
    }
    asm volatile("" : "+v"(tc0), "+v"(tc1), "+v"(tc2), "+v"(tc3));
    asm volatile("" : "+v"(tc4), "+v"(tc5), "+v"(tc6), "+v"(tc7));

    // STEP(CUR,NXT,INI): window reads of B_CUR (critical, first); plain init B_INI[l]=-inf
    // (off-path, no RMW); VALU tree; ds_max q into B_NXT[mslot]. SEL = s_{t-1}[n] (store lanes).
    #define STEP(CUR, NXT, INI, EV, SEL) { \
        float4 ra  = *(const float4*)&smem[(CUR)*64 + wb]; \
        float4 rb4 = *(const float4*)&smem[(CUR)*64 + wb + 4]; \
        smem[(INI)*64 + l] = NEGINF;                       /* init buffer t+1 (plain write) */ \
        float x01 = (j&1) ? ra.y  : ra.x; \
        float x23 = (j&1) ? ra.w  : ra.z; \
        float x45 = (j&1) ? rb4.y : rb4.x; \
        float x67 = (j&1) ? rb4.w : rb4.z; \
        float y0  = (j&2) ? x23 : x01; \
        float y1  = (j&2) ? x67 : x45; \
        SEL = (j&4) ? y1 : y0;                             /* s_{t-1}[n], off critical path */ \
        float w0 = ra.x  + tc0, w1 = ra.y  + tc1, w2 = ra.z  + tc2, w3 = ra.w  + tc3; \
        float w4 = rb4.x + tc4, w5 = rb4.y + tc5, w6 = rb4.z + tc6, w7 = rb4.w + tc7; \
        float m0 = fmaxf(fmaxf(w0, w1), w2); \
        float m1 = fmaxf(fmaxf(w3, w4), w5); \
        float m2 = fmaxf(w6, w7); \
        float q  = fmaxf(fmaxf(m0, m1), m2) + (EV);        /* q_c = fl(pr_c + e[n]) */ \
        (void)__hip_atomic_fetch_max(&smem[(NXT)*64 + mslot], q, \
                 __ATOMIC_RELAXED, __HIP_MEMORY_SCOPE_WORKGROUP);   /* ds_max_f32 */ \
    }

    float4 ebuf0 = er4[0];
    float4 ebuf1 = er4[1];

    // ---- t=0 init + pack 0 (t=1..3) ----
    float v0 = ebuf0.x + start[n];         // s0 = fl(em[0]+start), ref order
    smem[l]      = (l < NC) ? v0 : NEGINF; // B0 = s0 (+ -inf pads)
    smem[64 + l] = NEGINF;                 // B1 = -inf (B2,B3 init'd by t=1,t=2's ring writes)
    float p0 = v0, p1, p2;
    {
        float4 ev = ebuf0;
        ebuf0 = er4[2];
        float sel1, sel2, sel3;
        STEP(0, 1, 2, ev.y, sel1)          // t=1: sel1 = s0 dup, unused
        STEP(1, 2, 3, ev.z, sel2)          // t=2: sel2 = s1
        STEP(2, 3, 0, ev.w, sel3)          // t=3: sel3 = s2
        (void)sel1;
        p1 = sel2; p2 = sel3;
    }

    // ---- packs 1..4095; pack k stores pack k-1's quad at its first step ----
    for (int k = 1; k < NPACK; ++k) {
        float4 ev = (k & 1) ? ebuf1 : ebuf0;
        int kp = k + 2; if (kp > NPACK-1) kp = NPACK-1;
        if (k & 1) ebuf1 = er4[kp]; else ebuf0 = er4[kp];

        float selA, selB, selC, selD;
        STEP(3, 0, 1, ev.x, selA)          // t=4k:   selA = s_{4k-1} completes pack k-1
        if (do_store) *(float4*)(scp + (k-1)*84 + n*4) = make_float4(p0, p1, p2, selA);
        STEP(0, 1, 2, ev.y, selB)          // t=4k+1: selB = s_{4k}
        STEP(1, 2, 3, ev.z, selC)          // t=4k+2: selC = s_{4k+1}
        STEP(2, 3, 0, ev.w, selD)          // t=4k+3: selD = s_{4k+2}
        p0 = selB; p1 = selC; p2 = selD;
    }
    #undef STEP

    // ---- epilogue: s_{L-1} (t=16383, maxed into B3) via window select ----
    float slast;
    {
        float4 ra  = *(const float4*)&smem[3*64 + wb];
        float4 rb4 = *(const float4*)&smem[3*64 + wb + 4];
        float x01 = (j&1) ? ra.y  : ra.x;
        float x23 = (j&1) ? ra.w  : ra.z;
        float x45 = (j&1) ? rb4.y : rb4.x;
        float x67 = (j&1) ? rb4.w : rb4.z;
        float y0  = (j&2) ? x23 : x01;
        float y1  = (j&2) ? x67 : x45;
        slast = (j&4) ? y1 : y0;
    }
    if (do_store) {
        *(float4*)(scp + (NPACK-1)*84 + n*4) = make_float4(p0, p1, p2, slast);
        fin[n] = slast;
    }
    __syncthreads();
    if (l == 0) {
        float bv = fin[0] + endt[0]; int bt = 0;
        #pragma unroll
        for (int jj = 1; jj < NC; ++jj) {
            float v = fin[jj] + endt[jj];
            if (v > bv) { bv = v; bt = jj; }
        }
        last_tag[b] = bt;
    }
}

// ---------------- K2b: parallel backpointer recovery ----------------
// bp[t][n] = first p with fl(fl(s_{t-1}[p]+T[p][n])+e[t][n]) == s_t[n]
__global__ __launch_bounds__(256) void k_bp(
    const float* __restrict__ emT, const float* __restrict__ sc,
    const float* __restrict__ trans, uint8_t* __restrict__ bp)
{
    int wave = threadIdx.x >> 6;
    int lane = threadIdx.x & 63;
    int ne   = lane < NC ? lane : NC-1;

    int bidx  = blockIdx.x;
    int b     = bidx >> 7;                              // 128 blocks per batch
    int tbase = (bidx & 127) * (4*T_PER) + wave*T_PER;

    const float* emb = emT + (size_t)b * NC * L;
    const float* scp = sc  + (size_t)b * NC * L;
    uint8_t*     bpb = bp  + (size_t)b * L * NC;

    float tc[NC];
    #pragma unroll
    for (int pp = 0; pp < NC; ++pp) tc[pp] = trans[pp*NC + ne];

    for (int t = tbase; t < tbase + T_PER; ++t) {
        if (t == 0) continue;
        float target = scp[(t>>2)*84 + ne*4 + (t&3)];
        float e      = emb[(size_t)ne * L + t];
        const float* sp = scp + ((t-1)>>2)*84 + ((t-1)&3);
        int fi = 0;
        #pragma unroll
        for (int pp = NC-1; pp >= 0; --pp) {
            float cand = (sp[pp*4] + tc[pp]) + e;
            if (cand == target) fi = pp;
        }
        if (lane < NC) bpb[(size_t)t * NC + ne] = (uint8_t)fi;
    }
}

// ---------------- K3a: per-chunk jump tables, SEGMENTED chase (exact) ----------------
__global__ __launch_bounds__(64) void k_jump(
    const uint8_t* __restrict__ bp, uint8_t* __restrict__ J)
{
    __shared__ uint32_t lds4[CHUNK*NC/4];    // 5376 B of bp rows [cs..ce)
    __shared__ uint8_t  segJ[8*NC];          // 168 B
    int l   = threadIdx.x;
    int bid = blockIdx.x;
    int b   = bid / (NCHUNKS-1);
    int k   = bid % (NCHUNKS-1) + 1;         // chunks 1..63
    int cs  = k * CHUNK;

    const uint32_t* src = (const uint32_t*)(bp + (size_t)b * L * NC + (size_t)cs * NC);
    for (int i = l; i < CHUNK*NC/4; i += 64) lds4[i] = src[i];
    __syncthreads();
    const uint8_t* lb = (const uint8_t*)lds4;

    // 168 = 8 segs x 21 hyps; chase c -> (s=c/21, h=c%21), rows s*32+31 .. s*32
    int c0 = l, c1 = l + 63, c2 = l + 126;
    bool v2 = (c2 < 8*NC);
    int t0 = c0 % NC, t1 = c1 % NC, t2 = v2 ? (c2 % NC) : 0;
    int r0 = (c0 / NC) * 32, r1 = (c1 / NC) * 32, r2 = v2 ? (c2 / NC) * 32 : 0;
    for (int i = 31; i >= 0; --i) {          // 3 independent chains -> pipelined
        t0 = lb[(r0+i)*NC + t0];
        t1 = lb[(r1+i)*NC + t1];
        if (v2) t2 = lb[(r2+i)*NC + t2];
    }
    segJ[c0] = (uint8_t)t0;
    segJ[c1] = (uint8_t)t1;
    if (v2) segJ[c2] = (uint8_t)t2;
    __syncthreads();

    if (l < NC) {
        int tag = l;
        #pragma unroll
        for (int s = 7; s >= 0; --s) tag = segJ[s*NC + tag];
        J[((size_t)b * NCHUNKS + k) * NC + l] = (uint8_t)tag;
    }
}

// ---------------- K3b: thread chunk entries through jump tables (LDS-staged J) ----------------
__global__ __launch_bounds__(64) void k_seq(
    const uint8_t* __restrict__ J, const int* __restrict__ last_tag,
    uint8_t* __restrict__ ent)
{
    __shared__ uint32_t ldsJ4[NB*NCHUNKS*NC/4];   // 21504 B
    int l = threadIdx.x;
    const uint32_t* src = (const uint32_t*)J;
    for (int i = l; i < NB*NCHUNKS*NC/4; i += 64) ldsJ4[i] = src[i];
    __syncthreads();
    const uint8_t* lj = (const uint8_t*)ldsJ4;

    if (l < NB) {
        int b = l;
        int tag = last_tag[b];                       // tag at t = L-1
        ent[b * NCHUNKS + 63] = (uint8_t)tag;
        for (int k = NCHUNKS-1; k >= 1; --k) {
            tag = lj[((size_t)b * NCHUNKS + k) * NC + tag];
            ent[b * NCHUNKS + (k-1)] = (uint8_t)tag;
        }
    }
}

// ---------------- K3c: per-chunk output, SEGMENTED re-walk from exact seed ----------------
__global__ __launch_bounds__(64) void k_out(
    const uint8_t* __restrict__ bp, const uint8_t* __restrict__ ent,
    int* __restrict__ out)
{
    __shared__ uint32_t lds4[CHUNK*NC/4];
    __shared__ uint8_t  segJ[8*NC];
    __shared__ uint8_t  E[8];
    __shared__ int      tags[CHUNK];
    int l   = threadIdx.x;
    int bid = blockIdx.x;
    int b   = bid >> 6;
    int k   = bid & (NCHUNKS-1);
    int cs  = k * CHUNK;

    const uint32_t* src = (const uint32_t*)(bp + (size_t)b * L * NC + (size_t)cs * NC);
    for (int i = l; i < CHUNK*NC/4; i += 64) lds4[i] = src[i];
    __syncthreads();
    const uint8_t* lb = (const uint8_t*)lds4;

    // phase 2: segment tables (chunk 0 seg 0 crosses t=0: its result is never used)
    int c0 = l, c1 = l + 63, c2 = l + 126;
    bool v2 = (c2 < 8*NC);
    int t0 = c0 % NC, t1 = c1 % NC, t2 = v2 ? (c2 % NC) : 0;
    int r0 = (c0 / NC) * 32, r1 = (c1 / NC) * 32, r2 = v2 ? (c2 / NC) * 32 : 0;
    for (int i = 31; i >= 0; --i) {
        t0 = lb[(r0+i)*NC + t0];
        t1 = lb[(r1+i)*NC + t1];
        if (v2) t2 = lb[(r2+i)*NC + t2];
    }
    segJ[c0] = (uint8_t)(t0 & 31);           // mask: chunk-0/seg-0 garbage stays in-bounds
    segJ[c1] = (uint8_t)(t1 & 31);
    if (v2) segJ[c2] = (uint8_t)(t2 & 31);
    __syncthreads();

    // phase 3: compose segment entry tags E[s] = tag at position cs + 32s + 31
    if (l == 0) {
        int tag = ent[b * NCHUNKS + k];              // exact tag at ce-1
        E[7] = (uint8_t)tag;
        #pragma unroll
        for (int s = 7; s >= 1; --s) { tag = segJ[s*NC + tag]; E[s-1] = (uint8_t)tag; }
    }
    __syncthreads();

    // phase 4: 8 lanes re-walk their 32 rows
    if (l < 8) {
        int tag = E[l];
        int rb  = l * 32;
        for (int i = 31; i >= 0; --i) {              // t = cs+rb+i down to cs+rb
            tags[rb + i] = tag;
            tag = lb[(rb+i)*NC + tag];               // hop at t=0 (chunk 0) unused
        }
    }
    __syncthreads();

    int4* ob = (int4*)(out + (size_t)b * L + cs);
    ob[l] = ((const int4*)tags)[l];                  // 64 lanes x int4 = 256 ints
}

extern "C" void kernel_launch(void* const* d_in, const int* in_sizes, int n_in,
                              void* d_out, int out_size, void* d_ws, size_t ws_size,
                              hipStream_t stream) {
    const float* x  = (const float*)d_in[0];
    const float* w1 = (const float*)d_in[1];
    const float* b1 = (const float*)d_in[2];
    const float* w2 = (const float*)d_in[3];
    const float* b2 = (const float*)d_in[4];
    const float* st = (const float*)d_in[5];
    const float* en = (const float*)d_in[6];
    const float* tr = (const float*)d_in[7];
    int* out = (int*)d_out;

    char* ws = (char*)d_ws;
    float*   em = (float*)ws;                                    // em_T: 22,020,096 B
    float*   sc = (float*)(ws + (size_t)NB*L*NC*4);              // packed scores: 22,020,096 B
    uint8_t* bp = (uint8_t*)(ws + (size_t)NB*L*NC*8);            // 5,505,024 B
    int*     lt = (int*)(ws + (size_t)NB*L*NC*9);                // int[NB]
    // J/ent alias the em region: em is dead after k_bp completes (stream-ordered).
    uint8_t* J   = (uint8_t*)ws;                                 // NB*64*21 = 21,504 B
    uint8_t* ent = (uint8_t*)ws + 21504;                         // NB*64 = 1,024 B

    k_conv  <<<dim3(NB*L/256),       dim3(256), 0, stream>>>(x, w1, b1, w2, b2, em);
    k_scores<<<dim3(NB),             dim3(64),  0, stream>>>(em, st, en, tr, sc, lt);
    k_bp    <<<dim3(NB*128),         dim3(256), 0, stream>>>(em, sc, tr, bp);
    k_jump  <<<dim3(NB*(NCHUNKS-1)), dim3(64),  0, stream>>>(bp, J);
    k_seq   <<<dim3(1),              dim3(64),  0, stream>>>(J, lt, ent);
    k_out   <<<dim3(NB*NCHUNKS),     dim3(64),  0, stream>>>(bp, ent, out);
}

// Round 11
// 1975.628 us; speedup vs baseline: 1.1719x; 1.1062x over previous
//
#include <hip/hip_runtime.h>
#include <stdint.h>

#define NB 16
#define HH 128
#define WW 128
#define L (HH*WW)        // 16384
#define CIN 3
#define HID 256
#define NC 21
#define CHUNK 256
#define NCHUNKS (L/CHUNK)   // 64
#define T_PER 32            // t's per wave in k_bp
#define NPACK (L/4)         // 4096 packs of 4 timesteps

// ---------------- K1: conv -> fp32 emissions, TRANSPOSED em_T[b][c][t], LDS input tile ----------------
__global__ __launch_bounds__(256) void k_conv(
    const float* __restrict__ x, const float* __restrict__ w1,
    const float* __restrict__ b1, const float* __restrict__ w2,
    const float* __restrict__ b2, float* __restrict__ emT)
{
    __shared__ float xs[CIN*4*WW];        // 3 ic x 4 rows x 128 cols = 6144 B
    int tid = threadIdx.x;
    int g  = blockIdx.x * 256 + tid;      // 0..B*L-1
    int b  = g >> 14;
    int t0 = (blockIdx.x * 256) & (L-1);  // first t of block (multiple of 256)
    int y0 = t0 >> 7;                     // first of the block's 2 rows
    int dy = tid >> 7;                    // 0 or 1
    int xx = tid & (WW-1);
    int t  = t0 + tid;

    const float* xb = x + (size_t)b * CIN * L;
    for (int i = tid; i < CIN*4*WW; i += 256) {
        int ic  = i >> 9;                 // /512
        int rem = i & 511;
        int rr  = rem >> 7;               // 0..3
        int cc  = rem & 127;
        int row = y0 - 1 + rr;
        xs[i] = (row >= 0 && row < HH) ? xb[ic*L + (row<<7) + cc] : 0.f;
    }
    __syncthreads();

    double p[27];
    #pragma unroll
    for (int ic = 0; ic < CIN; ++ic) {
        #pragma unroll
        for (int ky = 0; ky < 3; ++ky) {
            #pragma unroll
            for (int kx = 0; kx < 3; ++kx) {
                int xc = xx + kx - 1;
                float v = (xc >= 0 && xc < WW) ? xs[ic*512 + (dy+ky)*128 + xc] : 0.f;
                p[ic*9 + ky*3 + kx] = (double)v;
            }
        }
    }

    double acc[NC];
    #pragma unroll
    for (int c = 0; c < NC; ++c) acc[c] = 0.0;

    #pragma unroll 2
    for (int oc = 0; oc < HID; ++oc) {
        double hv = 0.0;                              // conv1 accum
        #pragma unroll
        for (int j = 0; j < 27; ++j) hv += (double)w1[oc*27 + j] * p[j];
        float h32 = (float)hv;                        // round conv1 to fp32
        h32 = h32 + b1[oc];                           // fp32 elementwise bias
        h32 = fmaxf(h32, 0.f);                        // relu (fp32)
        double hd = (double)h32;
        #pragma unroll
        for (int c = 0; c < NC; ++c) acc[c] += (double)w2[c*HID + oc] * hd;
    }
    float* dstb = emT + (size_t)b * NC * L;
    #pragma unroll
    for (int c = 0; c < NC; ++c) {
        float e32 = (float)acc[c];                    // round conv2 to fp32
        dstb[(size_t)c * L + t] = e32 + b2[c];        // transposed store (coalesced in t)
    }
}

// ---------------- K2a: R7 structure, combine = plain write + 2-way ds_max ----------------
// s'[n] = fl( max_p fl(s[p]+T[p][n]) + e[n] ) — bitwise equal to ref by RNE monotonicity:
// q_c = fl(max_{p in W_c} fl(s[p]+T) + e) = max_{W_c} fl(fl(s+T)+e); slot n accumulates
// max(q0,q1,q2) over -inf base — q0 lands via PLAIN ds_write, q1/q2 via ds_max (2-way RMW
// instead of R7's 3-way). Candidate set identical to ref -> sc bit-identical.
// Ledger (cy/step): R7=229 (BEST), R5=237, R10=265, R8=283, R11=314, R6=325, R2=346, R1=421,
// R3=551. Laws: (1) only the LDS ALU combines cheaply (register-side >=40cy on chain);
// (2) issue-stream insertions between reads and ds_max cost their issue cycles (R10's select).
// R11 delta vs R7: ONE RMW pass removed from the critical slot (+1 plain write issue ~ +8cy,
// -1 sequential RMW ~ -16cy -> est ~221 cy/step). Order within step (all ops target NXT):
// wrxchg (init+readback, same as R7) -> plain write -> ds_max; wave DS ops execute in order;
// a "memory"-clobber asm pins write-before-max against compiler reordering (write overtaking
// max would drop q1,q2). Dumps: write dumps in slots {24..63} U {61,62,63}, max dumps in
// {24..44} U {63} — pads 21-23 only ever touched by wrxchg's -inf. Readback/sc bookkeeping,
// epilogue: byte-identical to R7.
#define NEGINF (-__builtin_huge_valf())

__global__ __launch_bounds__(64) void k_scores(
    const float* __restrict__ emT, const float* __restrict__ start,
    const float* __restrict__ endt, const float* __restrict__ trans,
    float* __restrict__ sc, int* __restrict__ last_tag)
{
    __shared__ float smem[128];            // two 64-float ping-pong buffers
    __shared__ float fin[NC];
    int l = threadIdx.x;
    int b = blockIdx.x;
    int c = l / 21; if (c > 2) c = 2;      // copy 0/1/2; lane 63 dups (2,20)
    int n = l - c*21; if (n > 20) n = 20;  // my state
    int wb = 8*c;                          // my p-window: floats [8c .. 8c+7]
    // write slot: copy 0 -> real slot n; others -> dump (l=21..23 -> 61..63, l>=24 -> l).
    int wslot = (c == 0) ? n : ((l < 24) ? 40 + l : l);
    // max slot: copies 1,2 (lanes 21..62) -> real slot n; copy 0 -> dump 24+l; lane 63 -> 63.
    int mslot = (l >= 21 && l < 63) ? n : ((l < 21) ? 24 + l : 63);

    const float4* er4 = (const float4*)(emT + ((size_t)b * NC + n) * L);
    float*        scp = sc + (size_t)b * NC * L;          // 84 floats per pack

    // 8 transition constants T[wb+i][n]; -inf for p>20 (window pad)
    float tc0, tc1, tc2, tc3, tc4, tc5, tc6, tc7;
    {
        int p0=wb, p1=wb+1, p2=wb+2, p3=wb+3, p4=wb+4, p5=wb+5, p6=wb+6, p7=wb+7;
        tc0 = trans[p0*NC + n];
        tc1 = trans[p1*NC + n];
        tc2 = trans[p2*NC + n];
        tc3 = trans[p3*NC + n];
        tc4 = trans[p4*NC + n];
        tc5 = (p5 < NC) ? trans[p5*NC + n] : NEGINF;
        tc6 = (p6 < NC) ? trans[p6*NC + n] : NEGINF;
        tc7 = (p7 < NC) ? trans[p7*NC + n] : NEGINF;
    }
    asm volatile("" : "+v"(tc0), "+v"(tc1), "+v"(tc2), "+v"(tc3));
    asm volatile("" : "+v"(tc4), "+v"(tc5), "+v"(tc6), "+v"(tc7));

    // STEP(CUR,NXT): window reads of CUR (critical, first); wrxchg NXT[l] -> RB = s_{t-2}[l]
    // and NXT[l]=-inf; VALU; plain write q (copy0 -> slot n); ds_max q (copies 1,2 -> slot n).
    #define STEP(CUR, NXT, EV, RB) { \
        float4 ra  = *(const float4*)&smem[(CUR)*64 + wb]; \
        float4 rb4 = *(const float4*)&smem[(CUR)*64 + wb + 4]; \
        RB = __hip_atomic_exchange(&smem[(NXT)*64 + l], NEGINF, \
                 __ATOMIC_RELAXED, __HIP_MEMORY_SCOPE_WORKGROUP);   /* ds_wrxchg_rtn_b32 */ \
        float w0 = ra.x  + tc0, w1 = ra.y  + tc1, w2 = ra.z  + tc2, w3 = ra.w  + tc3; \
        float w4 = rb4.x + tc4, w5 = rb4.y + tc5, w6 = rb4.z + tc6, w7 = rb4.w + tc7; \
        float m0 = fmaxf(fmaxf(w0, w1), w2); \
        float m1 = fmaxf(fmaxf(w3, w4), w5); \
        float m2 = fmaxf(w6, w7); \
        float q  = fmaxf(fmaxf(m0, m1), m2) + (EV);        /* q_c = fl(pr_c + e[n]) */ \
        smem[(NXT)*64 + wslot] = q;                        /* copy0 contribution, plain write */ \
        asm volatile("" ::: "memory");                     /* pin write before ds_max */ \
        (void)__hip_atomic_fetch_max(&smem[(NXT)*64 + mslot], q, \
                 __ATOMIC_RELAXED, __HIP_MEMORY_SCOPE_WORKGROUP);   /* 2-way ds_max_f32 */ \
    }

    float4 ebuf0 = er4[0];
    float4 ebuf1 = er4[1];

    // ---- t=0 init + pack 0 (t=1..3) ----
    float v0 = ebuf0.x + start[n];         // s0 = fl(em[0]+start), ref order
    smem[l] = (l < NC) ? v0 : NEGINF;      // buf0 = s0, slots 21..63 = -inf (buf1 init'd by t=1's wrxchg)
    float h0 = v0, h1;                     // two oldest pending quad entries
    {
        float4 ev = ebuf0;
        ebuf0 = er4[2];
        float rb1, rb2, rb3;
        STEP(0, 1, ev.y, rb1)              // t=1: rb1 = garbage (buf1 uninit), discarded
        STEP(1, 0, ev.z, rb2)              // t=2: rb2 = s0 (dup of v0), discarded
        STEP(0, 1, ev.w, rb3)              // t=3: rb3 = s1
        (void)rb1; (void)rb2;
        h1 = rb3;                          // h0 = s0, h1 = s1
    }

    // ---- packs 1..4095; pack k stores pack k-1's quad after its 2nd step ----
    for (int k = 1; k < NPACK; ++k) {
        float4 ev = (k & 1) ? ebuf1 : ebuf0;
        int kp = k + 2; if (kp > NPACK-1) kp = NPACK-1;
        if (k & 1) ebuf1 = er4[kp]; else ebuf0 = er4[kp];

        float rbA, rbB, rbC, rbD;
        STEP(1, 0, ev.x, rbA)              // t=4k:   rbA = s_{4k-2}
        STEP(0, 1, ev.y, rbB)              // t=4k+1: rbB = s_{4k-1}
        if (l < NC) *(float4*)(scp + (k-1)*84 + n*4) = make_float4(h0, h1, rbA, rbB);
        STEP(1, 0, ev.z, rbC)              // t=4k+2: rbC = s_{4k}
        STEP(0, 1, ev.w, rbD)              // t=4k+3: rbD = s_{4k+1}
        h0 = rbC; h1 = rbD;
    }
    #undef STEP

    // ---- epilogue: buf0 = s_{16382}, buf1 = s_{16383} (never exchanged after their writes) ----
    float s2last = smem[l];                // s_{L-2}[n] for l<21
    float s3last = smem[64 + l];           // s_{L-1}[n] for l<21
    if (l < NC) {
        *(float4*)(scp + (NPACK-1)*84 + n*4) = make_float4(h0, h1, s2last, s3last);
        fin[n] = s3last;
    }
    __syncthreads();
    if (l == 0) {
        float bv = fin[0] + endt[0]; int bt = 0;
        #pragma unroll
        for (int j = 1; j < NC; ++j) {
            float v = fin[j] + endt[j];
            if (v > bv) { bv = v; bt = j; }
        }
        last_tag[b] = bt;
    }
}

// ---------------- K2b: parallel backpointer recovery ----------------
// bp[t][n] = first p with fl(fl(s_{t-1}[p]+T[p][n])+e[t][n]) == s_t[n]
__global__ __launch_bounds__(256) void k_bp(
    const float* __restrict__ emT, const float* __restrict__ sc,
    const float* __restrict__ trans, uint8_t* __restrict__ bp)
{
    int wave = threadIdx.x >> 6;
    int lane = threadIdx.x & 63;
    int ne   = lane < NC ? lane : NC-1;

    int bidx  = blockIdx.x;
    int b     = bidx >> 7;                              // 128 blocks per batch
    int tbase = (bidx & 127) * (4*T_PER) + wave*T_PER;

    const float* emb = emT + (size_t)b * NC * L;
    const float* scp = sc  + (size_t)b * NC * L;
    uint8_t*     bpb = bp  + (size_t)b * L * NC;

    float tc[NC];
    #pragma unroll
    for (int pp = 0; pp < NC; ++pp) tc[pp] = trans[pp*NC + ne];

    for (int t = tbase; t < tbase + T_PER; ++t) {
        if (t == 0) continue;
        float target = scp[(t>>2)*84 + ne*4 + (t&3)];
        float e      = emb[(size_t)ne * L + t];
        const float* sp = scp + ((t-1)>>2)*84 + ((t-1)&3);
        int fi = 0;
        #pragma unroll
        for (int pp = NC-1; pp >= 0; --pp) {
            float cand = (sp[pp*4] + tc[pp]) + e;
            if (cand == target) fi = pp;
        }
        if (lane < NC) bpb[(size_t)t * NC + ne] = (uint8_t)fi;
    }
}

// ---------------- K3a: per-chunk jump tables, SEGMENTED chase (exact) ----------------
__global__ __launch_bounds__(64) void k_jump(
    const uint8_t* __restrict__ bp, uint8_t* __restrict__ J)
{
    __shared__ uint32_t lds4[CHUNK*NC/4];    // 5376 B of bp rows [cs..ce)
    __shared__ uint8_t  segJ[8*NC];          // 168 B
    int l   = threadIdx.x;
    int bid = blockIdx.x;
    int b   = bid / (NCHUNKS-1);
    int k   = bid % (NCHUNKS-1) + 1;         // chunks 1..63
    int cs  = k * CHUNK;

    const uint32_t* src = (const uint32_t*)(bp + (size_t)b * L * NC + (size_t)cs * NC);
    for (int i = l; i < CHUNK*NC/4; i += 64) lds4[i] = src[i];
    __syncthreads();
    const uint8_t* lb = (const uint8_t*)lds4;

    // 168 = 8 segs x 21 hyps; chase c -> (s=c/21, h=c%21), rows s*32+31 .. s*32
    int c0 = l, c1 = l + 63, c2 = l + 126;
    bool v2 = (c2 < 8*NC);
    int t0 = c0 % NC, t1 = c1 % NC, t2 = v2 ? (c2 % NC) : 0;
    int r0 = (c0 / NC) * 32, r1 = (c1 / NC) * 32, r2 = v2 ? (c2 / NC) * 32 : 0;
    for (int i = 31; i >= 0; --i) {          // 3 independent chains -> pipelined
        t0 = lb[(r0+i)*NC + t0];
        t1 = lb[(r1+i)*NC + t1];
        if (v2) t2 = lb[(r2+i)*NC + t2];
    }
    segJ[c0] = (uint8_t)t0;
    segJ[c1] = (uint8_t)t1;
    if (v2) segJ[c2] = (uint8_t)t2;
    __syncthreads();

    if (l < NC) {
        int tag = l;
        #pragma unroll
        for (int s = 7; s >= 0; --s) tag = segJ[s*NC + tag];
        J[((size_t)b * NCHUNKS + k) * NC + l] = (uint8_t)tag;
    }
}

// ---------------- K3b: thread chunk entries through jump tables (LDS-staged J) ----------------
__global__ __launch_bounds__(64) void k_seq(
    const uint8_t* __restrict__ J, const int* __restrict__ last_tag,
    uint8_t* __restrict__ ent)
{
    __shared__ uint32_t ldsJ4[NB*NCHUNKS*NC/4];   // 21504 B
    int l = threadIdx.x;
    const uint32_t* src = (const uint32_t*)J;
    for (int i = l; i < NB*NCHUNKS*NC/4; i += 64) ldsJ4[i] = src[i];
    __syncthreads();
    const uint8_t* lj = (const uint8_t*)ldsJ4;

    if (l < NB) {
        int b = l;
        int tag = last_tag[b];                       // tag at t = L-1
        ent[b * NCHUNKS + 63] = (uint8_t)tag;
        for (int k = NCHUNKS-1; k >= 1; --k) {
            tag = lj[((size_t)b * NCHUNKS + k) * NC + tag];
            ent[b * NCHUNKS + (k-1)] = (uint8_t)tag;
        }
    }
}

// ---------------- K3c: per-chunk output, SEGMENTED re-walk from exact seed ----------------
__global__ __launch_bounds__(64) void k_out(
    const uint8_t* __restrict__ bp, const uint8_t* __restrict__ ent,
    int* __restrict__ out)
{
    __shared__ uint32_t lds4[CHUNK*NC/4];
    __shared__ uint8_t  segJ[8*NC];
    __shared__ uint8_t  E[8];
    __shared__ int      tags[CHUNK];
    int l   = threadIdx.x;
    int bid = blockIdx.x;
    int b   = bid >> 6;
    int k   = bid & (NCHUNKS-1);
    int cs  = k * CHUNK;

    const uint32_t* src = (const uint32_t*)(bp + (size_t)b * L * NC + (size_t)cs * NC);
    for (int i = l; i < CHUNK*NC/4; i += 64) lds4[i] = src[i];
    __syncthreads();
    const uint8_t* lb = (const uint8_t*)lds4;

    // phase 2: segment tables (chunk 0 seg 0 crosses t=0: its result is never used)
    int c0 = l, c1 = l + 63, c2 = l + 126;
    bool v2 = (c2 < 8*NC);
    int t0 = c0 % NC, t1 = c1 % NC, t2 = v2 ? (c2 % NC) : 0;
    int r0 = (c0 / NC) * 32, r1 = (c1 / NC) * 32, r2 = v2 ? (c2 / NC) * 32 : 0;
    for (int i = 31; i >= 0; --i) {
        t0 = lb[(r0+i)*NC + t0];
        t1 = lb[(r1+i)*NC + t1];
        if (v2) t2 = lb[(r2+i)*NC + t2];
    }
    segJ[c0] = (uint8_t)(t0 & 31);           // mask: chunk-0/seg-0 garbage stays in-bounds
    segJ[c1] = (uint8_t)(t1 & 31);
    if (v2) segJ[c2] = (uint8_t)(t2 & 31);
    __syncthreads();

    // phase 3: compose segment entry tags E[s] = tag at position cs + 32s + 31
    if (l == 0) {
        int tag = ent[b * NCHUNKS + k];              // exact tag at ce-1
        E[7] = (uint8_t)tag;
        #pragma unroll
        for (int s = 7; s >= 1; --s) { tag = segJ[s*NC + tag]; E[s-1] = (uint8_t)tag; }
    }
    __syncthreads();

    // phase 4: 8 lanes re-walk their 32 rows
    if (l < 8) {
        int tag = E[l];
        int rb  = l * 32;
        for (int i = 31; i >= 0; --i) {              // t = cs+rb+i down to cs+rb
            tags[rb + i] = tag;
            tag = lb[(rb+i)*NC + tag];               // hop at t=0 (chunk 0) unused
        }
    }
    __syncthreads();

    int4* ob = (int4*)(out + (size_t)b * L + cs);
    ob[l] = ((const int4*)tags)[l];                  // 64 lanes x int4 = 256 ints
}

extern "C" void kernel_launch(void* const* d_in, const int* in_sizes, int n_in,
                              void* d_out, int out_size, void* d_ws, size_t ws_size,
                              hipStream_t stream) {
    const float* x  = (const float*)d_in[0];
    const float* w1 = (const float*)d_in[1];
    const float* b1 = (const float*)d_in[2];
    const float* w2 = (const float*)d_in[3];
    const float* b2 = (const float*)d_in[4];
    const float* st = (const float*)d_in[5];
    const float* en = (const float*)d_in[6];
    const float* tr = (const float*)d_in[7];
    int* out = (int*)d_out;

    char* ws = (char*)d_ws;
    float*   em = (float*)ws;                                    // em_T: 22,020,096 B
    float*   sc = (float*)(ws + (size_t)NB*L*NC*4);              // packed scores: 22,020,096 B
    uint8_t* bp = (uint8_t*)(ws + (size_t)NB*L*NC*8);            // 5,505,024 B
    int*     lt = (int*)(ws + (size_t)NB*L*NC*9);                // int[NB]
    // J/ent alias the em region: em is dead after k_bp completes (stream-ordered).
    uint8_t* J   = (uint8_t*)ws;                                 // NB*64*21 = 21,504 B
    uint8_t* ent = (uint8_t*)ws + 21504;                         // NB*64 = 1,024 B

    k_conv  <<<dim3(NB*L/256),       dim3(256), 0, stream>>>(x, w1, b1, w2, b2, em);
    k_scores<<<dim3(NB),             dim3(64),  0, stream>>>(em, st, en, tr, sc, lt);
    k_bp    <<<dim3(NB*128),         dim3(256), 0, stream>>>(em, sc, tr, bp);
    k_jump  <<<dim3(NB*(NCHUNKS-1)), dim3(64),  0, stream>>>(bp, J);
    k_seq   <<<dim3(1),              dim3(64),  0, stream>>>(J, lt, ent);
    k_out   <<<dim3(NB*NCHUNKS),     dim3(64),  0, stream>>>(bp, ent, out);
}